// Round 4
// baseline (538.997 us; speedup 1.0000x reference)
//
#include <hip/hip_runtime.h>

#define FP8_MAX_F 448.0f

static constexpr int M = 8192;   // 4*2048
static constexpr int N = 8192;
static constexpr int K = 4096;

typedef __attribute__((ext_vector_type(4))) int i32x4;

#define AS1 __attribute__((address_space(1)))
#define AS3 __attribute__((address_space(3)))
#define BARRIER() asm volatile("s_barrier" ::: "memory")
#define VMCNT(n)  asm volatile("s_waitcnt vmcnt(" #n ")" ::: "memory")

// ---------------- amax over both tensors (exact, bit-trick atomicMax) --------
__global__ void amax_kernel(const float* __restrict__ x, const float* __restrict__ w,
                            unsigned* __restrict__ out) {
    const long n4x = (long)M * K / 4;
    const long n4t = n4x + (long)N * K / 4;
    unsigned lx = 0u, lw = 0u;
    const long stride = (long)gridDim.x * blockDim.x;
    for (long i = (long)blockIdx.x * blockDim.x + threadIdx.x; i < n4t; i += stride) {
        if (i < n4x) {
            float4 v = ((const float4*)x)[i];
            unsigned a0 = __float_as_uint(v.x) & 0x7fffffffu;
            unsigned a1 = __float_as_uint(v.y) & 0x7fffffffu;
            unsigned a2 = __float_as_uint(v.z) & 0x7fffffffu;
            unsigned a3 = __float_as_uint(v.w) & 0x7fffffffu;
            lx = max(lx, max(max(a0, a1), max(a2, a3)));
        } else {
            float4 v = ((const float4*)w)[i - n4x];
            unsigned a0 = __float_as_uint(v.x) & 0x7fffffffu;
            unsigned a1 = __float_as_uint(v.y) & 0x7fffffffu;
            unsigned a2 = __float_as_uint(v.z) & 0x7fffffffu;
            unsigned a3 = __float_as_uint(v.w) & 0x7fffffffu;
            lw = max(lw, max(max(a0, a1), max(a2, a3)));
        }
    }
    #pragma unroll
    for (int off = 32; off > 0; off >>= 1) {
        lx = max(lx, (unsigned)__shfl_down((int)lx, off, 64));
        lw = max(lw, (unsigned)__shfl_down((int)lw, off, 64));
    }
    __shared__ unsigned smx[4], smw[4];
    if ((threadIdx.x & 63) == 0) { smx[threadIdx.x >> 6] = lx; smw[threadIdx.x >> 6] = lw; }
    __syncthreads();
    if (threadIdx.x == 0) {
        atomicMax(&out[0], max(max(smx[0], smx[1]), max(smx[2], smx[3])));
        atomicMax(&out[1], max(max(smw[0], smw[1]), max(smw[2], smw[3])));
    }
}

// ---------------- quantize both tensors to int8 codes, pre-swizzled layout ---
// Logical code (row r, k) stored with its 16B chunk XOR-permuted within each
// 64B k-group: chunk' = (k>>4)&3 XOR ((r>>1)&3). GEMM stages linearly
// (global_load_lds) and applies the same XOR on ds_read (T2, rule 21).
__device__ __forceinline__ signed char quant1(float v, float s) {
    float f = fminf(fmaxf(v * s, -FP8_MAX_F), FP8_MAX_F);
    return (signed char)(int)rintf(f / FP8_MAX_F * 127.0f);
}

__global__ void quant_kernel(const float* __restrict__ x, const float* __restrict__ w,
                             signed char* __restrict__ qx, signed char* __restrict__ qw,
                             const unsigned* __restrict__ amax_bits) {
    const float ax = fmaxf(__uint_as_float(amax_bits[0]), 1e-12f);
    const float aw = fmaxf(__uint_as_float(amax_bits[1]), 1e-12f);
    const float sxv = FP8_MAX_F / ax;
    const float swv = FP8_MAX_F / aw;
    const long cx = (long)M * K / 16;
    const long ct = cx + (long)N * K / 16;
    const long stride = (long)gridDim.x * blockDim.x;
    for (long ci = (long)blockIdx.x * blockDim.x + threadIdx.x; ci < ct; ci += stride) {
        const float* src; signed char* dst; float s; long c;
        if (ci < cx) { src = x; dst = qx; s = sxv; c = ci; }
        else         { src = w; dst = qw; s = swv; c = ci - cx; }
        const long r = c >> 8;              // K/16 = 256 chunks per row
        const int  cr = (int)(c & 255);
        const float4* in = (const float4*)(src + r * K + cr * 16);
        signed char ob[16];
        #pragma unroll
        for (int j = 0; j < 4; ++j) {
            float4 v = in[j];
            ob[j * 4 + 0] = quant1(v.x, s);
            ob[j * 4 + 1] = quant1(v.y, s);
            ob[j * 4 + 2] = quant1(v.z, s);
            ob[j * 4 + 3] = quant1(v.w, s);
        }
        const int osub = (cr & 3) ^ ((int)(r >> 1) & 3);
        *(int4*)(dst + r * K + ((long)((cr & ~3) + osub)) * 16) = *(const int4*)ob;
    }
}

// ---------------- int8 GEMM: C[m][n] = sum_k A[m][k]*B[n][k] ----------------
// 256x256 tile, BK=64, 512 threads = 8 waves (2M x 4N), wave output 128x64.
// 4-deep circular LDS buffer; register-prefetched fragments (tile t+1's 12
// ds_reads issue in tile t's read segment); ONE merged 32-MFMA burst per tile
// between 2 barriers (halves the exposed non-MFMA segments vs 4-barrier R3).
// Counted vmcnt(4) in main loop (tail ladder 4 -> 0), setprio around MFMA,
// T2 swizzled ds_read, T1 XCD-aware block swizzle.
__global__ __launch_bounds__(512, 2) void gemm_i8_kernel(
    const signed char* __restrict__ Aq, const signed char* __restrict__ Bq,
    float* __restrict__ C, const unsigned* __restrict__ amax_bits)
{
    __shared__ signed char lds[4][2][256 * 64];   // [buf][A/B][row*64 + col]

    const int tid  = threadIdx.x;
    const int wid  = tid >> 6;
    const int lane = tid & 63;
    const int wm = wid >> 2;          // 0..1  (M half)
    const int wn = wid & 3;           // 0..3  (N quarter)
    const int fr = lane & 15;
    const int fq = lane >> 4;

    // T1: bijective XCD swizzle (1024 blocks, 8 XCDs): XCD k owns a 4-row
    // strip of N-tiles -> B panels stay L2-resident per XCD.
    const int bid = blockIdx.x;
    const int swz = (bid & 7) * 128 + (bid >> 3);
    const long row0 = (long)(swz & 31) * 256;
    const long col0 = (long)(swz >> 5) * 256;

    const signed char* Ablk = Aq + row0 * K;
    const signed char* Bblk = Bq + col0 * K;

    // staging: one issue = 512 thr x 16B = 128 rows x 64B (linear LDS dest)
    const long stag_off = (long)(tid >> 2) * K + (long)(tid & 3) * 16;

    // swizzled ds_read offsets
    const int arow = wm * 128 + fr;
    const int aoff = arow * 64 + ((fq ^ ((arow >> 1) & 3)) * 16);
    const int brow = wn * 64 + fr;
    const int boff = brow * 64 + ((fq ^ ((brow >> 1) & 3)) * 16);

    i32x4 acc[8][4] = {};
    i32x4 afR[2][8];      // double-buffered A fragments (tile parity)
    i32x4 bR[2][4];       // double-buffered B fragments

#define STAGE_AB(st) do { \
        const signed char* ga = Ablk + (long)(st) * 64 + stag_off; \
        const signed char* gb = Bblk + (long)(st) * 64 + stag_off; \
        signed char* lA = &lds[(st) & 3][0][0]; \
        signed char* lB = &lds[(st) & 3][1][0]; \
        __builtin_amdgcn_global_load_lds((const AS1 void*)ga, \
            (AS3 void*)(lA + wid * 1024), 16, 0, 0); \
        __builtin_amdgcn_global_load_lds((const AS1 void*)(ga + 128L * K), \
            (AS3 void*)(lA + 8192 + wid * 1024), 16, 0, 0); \
        __builtin_amdgcn_global_load_lds((const AS1 void*)gb, \
            (AS3 void*)(lB + wid * 1024), 16, 0, 0); \
        __builtin_amdgcn_global_load_lds((const AS1 void*)(gb + 128L * K), \
            (AS3 void*)(lB + 8192 + wid * 1024), 16, 0, 0); \
    } while (0)

#define READS(t1, NXT) do { \
        const signed char* la = &lds[(t1) & 3][0][0]; \
        const signed char* lb = &lds[(t1) & 3][1][0]; \
        _Pragma("unroll") \
        for (int mi = 0; mi < 8; ++mi) \
            afR[NXT][mi] = *(const i32x4*)(la + aoff + mi * 1024); \
        _Pragma("unroll") \
        for (int ni = 0; ni < 4; ++ni) \
            bR[NXT][ni] = *(const i32x4*)(lb + boff + ni * 1024); \
    } while (0)

#define MFMA32(CUR) do { \
        BARRIER(); \
        __builtin_amdgcn_s_setprio(1); \
        _Pragma("unroll") \
        for (int mi = 0; mi < 8; ++mi) { \
            _Pragma("unroll") \
            for (int ni = 0; ni < 4; ++ni) \
                acc[mi][ni] = __builtin_amdgcn_mfma_i32_16x16x64_i8( \
                    afR[CUR][mi], bR[CUR][ni], acc[mi][ni], 0, 0, 0); \
        } \
        __builtin_amdgcn_s_setprio(0); \
        BARRIER(); \
    } while (0)

    // prologue: stage tiles 0,1,2 (12 issues); drain to 4 -> tiles 0,1 resident
    STAGE_AB(0); STAGE_AB(1); STAGE_AB(2);
    VMCNT(4);
    BARRIER();
    READS(0, 0);

    // main loop: tiles 0..59 (stages 3..62, reads t+1, one MFMA burst each)
    #pragma unroll 1
    for (int t = 0; t < 60; t += 2) {
        READS(t + 1, 1);
        STAGE_AB(t + 3);
        VMCNT(4);
        MFMA32(0);

        READS(t + 2, 0);
        STAGE_AB(t + 4);
        VMCNT(4);
        MFMA32(1);
    }
    // tail: t=60 stages 63 (last), then vmcnt ladder 4 -> 0
    READS(61, 1); STAGE_AB(63); VMCNT(4); MFMA32(0);   // t=60
    READS(62, 0);               VMCNT(0); MFMA32(1);   // t=61
    READS(63, 1);                         MFMA32(0);   // t=62
    MFMA32(1);                                         // t=63

#undef MFMA32
#undef READS
#undef STAGE_AB

    const float ax = fmaxf(__uint_as_float(amax_bits[0]), 1e-12f);
    const float aw = fmaxf(__uint_as_float(amax_bits[1]), 1e-12f);
    const float factor = ax * aw * (1.0f / (127.0f * 127.0f));

    #pragma unroll
    for (int mi = 0; mi < 8; ++mi) {
        #pragma unroll
        for (int ni = 0; ni < 4; ++ni) {
            const long col = col0 + wn * 64 + ni * 16 + fr;
            #pragma unroll
            for (int j = 0; j < 4; ++j) {
                const long row = row0 + wm * 128 + mi * 16 + fq * 4 + j;
                C[row * N + col] = (float)acc[mi][ni][j] * factor;
            }
        }
    }
}

extern "C" void kernel_launch(void* const* d_in, const int* in_sizes, int n_in,
                              void* d_out, int out_size, void* d_ws, size_t ws_size,
                              hipStream_t stream) {
    const float* x = (const float*)d_in[0];   // [4,2048,4096] -> [M,K]
    const float* w = (const float*)d_in[1];   // [N,K]
    float* out = (float*)d_out;               // [M,N]

    unsigned char* ws = (unsigned char*)d_ws;
    unsigned* amax = (unsigned*)ws;                        // 2 uints
    signed char* aq = (signed char*)(ws + 256);            // M*K int8 (swizzled)
    signed char* wq = aq + (long)M * K;                    // N*K int8 (swizzled)

    hipMemsetAsync(amax, 0, 2 * sizeof(unsigned), stream);
    amax_kernel<<<2048, 256, 0, stream>>>(x, w, amax);
    quant_kernel<<<4096, 256, 0, stream>>>(x, w, aq, wq, amax);

    gemm_i8_kernel<<<1024, 512, 0, stream>>>(aq, wq, out, amax);
}

// Round 5
// 442.522 us; speedup vs baseline: 1.2180x; 1.2180x over previous
//
#include <hip/hip_runtime.h>

#define FP8_MAX_F 448.0f

static constexpr int M = 8192;   // 4*2048
static constexpr int N = 8192;
static constexpr int K = 4096;

typedef __attribute__((ext_vector_type(4))) int i32x4;

#define AS1 __attribute__((address_space(1)))
#define AS3 __attribute__((address_space(3)))
#define BARRIER() asm volatile("s_barrier" ::: "memory")
#define VMCNT(n)  asm volatile("s_waitcnt vmcnt(" #n ")" ::: "memory")

// ---------------- amax over both tensors (exact, bit-trick atomicMax) --------
__global__ void amax_kernel(const float* __restrict__ x, const float* __restrict__ w,
                            unsigned* __restrict__ out) {
    const long n4x = (long)M * K / 4;
    const long n4t = n4x + (long)N * K / 4;
    unsigned lx = 0u, lw = 0u;
    const long stride = (long)gridDim.x * blockDim.x;
    for (long i = (long)blockIdx.x * blockDim.x + threadIdx.x; i < n4t; i += stride) {
        if (i < n4x) {
            float4 v = ((const float4*)x)[i];
            unsigned a0 = __float_as_uint(v.x) & 0x7fffffffu;
            unsigned a1 = __float_as_uint(v.y) & 0x7fffffffu;
            unsigned a2 = __float_as_uint(v.z) & 0x7fffffffu;
            unsigned a3 = __float_as_uint(v.w) & 0x7fffffffu;
            lx = max(lx, max(max(a0, a1), max(a2, a3)));
        } else {
            float4 v = ((const float4*)w)[i - n4x];
            unsigned a0 = __float_as_uint(v.x) & 0x7fffffffu;
            unsigned a1 = __float_as_uint(v.y) & 0x7fffffffu;
            unsigned a2 = __float_as_uint(v.z) & 0x7fffffffu;
            unsigned a3 = __float_as_uint(v.w) & 0x7fffffffu;
            lw = max(lw, max(max(a0, a1), max(a2, a3)));
        }
    }
    #pragma unroll
    for (int off = 32; off > 0; off >>= 1) {
        lx = max(lx, (unsigned)__shfl_down((int)lx, off, 64));
        lw = max(lw, (unsigned)__shfl_down((int)lw, off, 64));
    }
    __shared__ unsigned smx[4], smw[4];
    if ((threadIdx.x & 63) == 0) { smx[threadIdx.x >> 6] = lx; smw[threadIdx.x >> 6] = lw; }
    __syncthreads();
    if (threadIdx.x == 0) {
        atomicMax(&out[0], max(max(smx[0], smx[1]), max(smx[2], smx[3])));
        atomicMax(&out[1], max(max(smw[0], smw[1]), max(smw[2], smw[3])));
    }
}

// ---------------- quantize both tensors to int8 codes, pre-swizzled layout ---
// Logical code (row r, k) stored with its 16B chunk XOR-permuted within each
// 64B k-group: chunk' = (k>>4)&3 XOR ((r>>1)&3). GEMM stages linearly
// (global_load_lds) and applies the same XOR on ds_read (T2, rule 21).
__device__ __forceinline__ signed char quant1(float v, float s) {
    float f = fminf(fmaxf(v * s, -FP8_MAX_F), FP8_MAX_F);
    return (signed char)(int)rintf(f / FP8_MAX_F * 127.0f);
}

__global__ void quant_kernel(const float* __restrict__ x, const float* __restrict__ w,
                             signed char* __restrict__ qx, signed char* __restrict__ qw,
                             const unsigned* __restrict__ amax_bits) {
    const float ax = fmaxf(__uint_as_float(amax_bits[0]), 1e-12f);
    const float aw = fmaxf(__uint_as_float(amax_bits[1]), 1e-12f);
    const float sxv = FP8_MAX_F / ax;
    const float swv = FP8_MAX_F / aw;
    const long cx = (long)M * K / 16;
    const long ct = cx + (long)N * K / 16;
    const long stride = (long)gridDim.x * blockDim.x;
    for (long ci = (long)blockIdx.x * blockDim.x + threadIdx.x; ci < ct; ci += stride) {
        const float* src; signed char* dst; float s; long c;
        if (ci < cx) { src = x; dst = qx; s = sxv; c = ci; }
        else         { src = w; dst = qw; s = swv; c = ci - cx; }
        const long r = c >> 8;              // K/16 = 256 chunks per row
        const int  cr = (int)(c & 255);
        const float4* in = (const float4*)(src + r * K + cr * 16);
        signed char ob[16];
        #pragma unroll
        for (int j = 0; j < 4; ++j) {
            float4 v = in[j];
            ob[j * 4 + 0] = quant1(v.x, s);
            ob[j * 4 + 1] = quant1(v.y, s);
            ob[j * 4 + 2] = quant1(v.z, s);
            ob[j * 4 + 3] = quant1(v.w, s);
        }
        const int osub = (cr & 3) ^ ((int)(r >> 1) & 3);
        *(int4*)(dst + r * K + ((long)((cr & ~3) + osub)) * 16) = *(const int4*)ob;
    }
}

// ---------------- int8 GEMM: C[m][n] = sum_k A[m][k]*B[n][k] ----------------
// 256x256 tile, BK=64, 512 threads = 8 waves (2M x 4N), wave output 128x64.
// 4-deep circular LDS buffer; register-prefetched fragments (tile t+1's 12
// ds_reads issue in tile t's read segment); ONE merged 32-MFMA burst per tile
// between 2 barriers. Counted vmcnt(4) in main loop (tail ladder 4 -> 0),
// setprio around MFMA, T2 swizzled ds_read. Default grid mapping
// (dim3(32,32), blockIdx.x = row tile) — R4's manual XCD swizzle blew up
// FETCH_SIZE 209->542 MB; default dispatch keeps panels L2-resident.
__global__ __launch_bounds__(512, 2) void gemm_i8_kernel(
    const signed char* __restrict__ Aq, const signed char* __restrict__ Bq,
    float* __restrict__ C, const unsigned* __restrict__ amax_bits)
{
    __shared__ signed char lds[4][2][256 * 64];   // [buf][A/B][row*64 + col]

    const int tid  = threadIdx.x;
    const int wid  = tid >> 6;
    const int lane = tid & 63;
    const int wm = wid >> 2;          // 0..1  (M half)
    const int wn = wid & 3;           // 0..3  (N quarter)
    const int fr = lane & 15;
    const int fq = lane >> 4;

    const long row0 = (long)blockIdx.x * 256;
    const long col0 = (long)blockIdx.y * 256;

    const signed char* Ablk = Aq + row0 * K;
    const signed char* Bblk = Bq + col0 * K;

    // staging: one issue = 512 thr x 16B = 128 rows x 64B (linear LDS dest)
    const long stag_off = (long)(tid >> 2) * K + (long)(tid & 3) * 16;

    // swizzled ds_read offsets
    const int arow = wm * 128 + fr;
    const int aoff = arow * 64 + ((fq ^ ((arow >> 1) & 3)) * 16);
    const int brow = wn * 64 + fr;
    const int boff = brow * 64 + ((fq ^ ((brow >> 1) & 3)) * 16);

    i32x4 acc[8][4] = {};
    i32x4 afR[2][8];      // double-buffered A fragments (tile parity)
    i32x4 bR[2][4];       // double-buffered B fragments

#define STAGE_AB(st) do { \
        const signed char* ga = Ablk + (long)(st) * 64 + stag_off; \
        const signed char* gb = Bblk + (long)(st) * 64 + stag_off; \
        signed char* lA = &lds[(st) & 3][0][0]; \
        signed char* lB = &lds[(st) & 3][1][0]; \
        __builtin_amdgcn_global_load_lds((const AS1 void*)ga, \
            (AS3 void*)(lA + wid * 1024), 16, 0, 0); \
        __builtin_amdgcn_global_load_lds((const AS1 void*)(ga + 128L * K), \
            (AS3 void*)(lA + 8192 + wid * 1024), 16, 0, 0); \
        __builtin_amdgcn_global_load_lds((const AS1 void*)gb, \
            (AS3 void*)(lB + wid * 1024), 16, 0, 0); \
        __builtin_amdgcn_global_load_lds((const AS1 void*)(gb + 128L * K), \
            (AS3 void*)(lB + 8192 + wid * 1024), 16, 0, 0); \
    } while (0)

#define READS(t1, NXT) do { \
        const signed char* la = &lds[(t1) & 3][0][0]; \
        const signed char* lb = &lds[(t1) & 3][1][0]; \
        _Pragma("unroll") \
        for (int mi = 0; mi < 8; ++mi) \
            afR[NXT][mi] = *(const i32x4*)(la + aoff + mi * 1024); \
        _Pragma("unroll") \
        for (int ni = 0; ni < 4; ++ni) \
            bR[NXT][ni] = *(const i32x4*)(lb + boff + ni * 1024); \
    } while (0)

#define MFMA32(CUR) do { \
        BARRIER(); \
        __builtin_amdgcn_s_setprio(1); \
        _Pragma("unroll") \
        for (int mi = 0; mi < 8; ++mi) { \
            _Pragma("unroll") \
            for (int ni = 0; ni < 4; ++ni) \
                acc[mi][ni] = __builtin_amdgcn_mfma_i32_16x16x64_i8( \
                    afR[CUR][mi], bR[CUR][ni], acc[mi][ni], 0, 0, 0); \
        } \
        __builtin_amdgcn_s_setprio(0); \
        BARRIER(); \
    } while (0)

    // prologue: stage tiles 0,1,2 (12 issues); drain to 4 -> tiles 0,1 resident
    STAGE_AB(0); STAGE_AB(1); STAGE_AB(2);
    VMCNT(4);
    BARRIER();
    READS(0, 0);

    // main loop: tiles 0..59 (stages 3..62, reads t+1, one MFMA burst each)
    #pragma unroll 1
    for (int t = 0; t < 60; t += 2) {
        READS(t + 1, 1);
        STAGE_AB(t + 3);
        VMCNT(4);
        MFMA32(0);

        READS(t + 2, 0);
        STAGE_AB(t + 4);
        VMCNT(4);
        MFMA32(1);
    }
    // tail: t=60 stages 63 (last), then vmcnt ladder 4 -> 0
    READS(61, 1); STAGE_AB(63); VMCNT(4); MFMA32(0);   // t=60
    READS(62, 0);               VMCNT(0); MFMA32(1);   // t=61
    READS(63, 1);                         MFMA32(0);   // t=62
    MFMA32(1);                                         // t=63

#undef MFMA32
#undef READS
#undef STAGE_AB

    const float ax = fmaxf(__uint_as_float(amax_bits[0]), 1e-12f);
    const float aw = fmaxf(__uint_as_float(amax_bits[1]), 1e-12f);
    const float factor = ax * aw * (1.0f / (127.0f * 127.0f));

    #pragma unroll
    for (int mi = 0; mi < 8; ++mi) {
        #pragma unroll
        for (int ni = 0; ni < 4; ++ni) {
            const long col = col0 + wn * 64 + ni * 16 + fr;
            #pragma unroll
            for (int j = 0; j < 4; ++j) {
                const long row = row0 + wm * 128 + mi * 16 + fq * 4 + j;
                C[row * N + col] = (float)acc[mi][ni][j] * factor;
            }
        }
    }
}

extern "C" void kernel_launch(void* const* d_in, const int* in_sizes, int n_in,
                              void* d_out, int out_size, void* d_ws, size_t ws_size,
                              hipStream_t stream) {
    const float* x = (const float*)d_in[0];   // [4,2048,4096] -> [M,K]
    const float* w = (const float*)d_in[1];   // [N,K]
    float* out = (float*)d_out;               // [M,N]

    unsigned char* ws = (unsigned char*)d_ws;
    unsigned* amax = (unsigned*)ws;                        // 2 uints
    signed char* aq = (signed char*)(ws + 256);            // M*K int8 (swizzled)
    signed char* wq = aq + (long)M * K;                    // N*K int8 (swizzled)

    hipMemsetAsync(amax, 0, 2 * sizeof(unsigned), stream);
    amax_kernel<<<2048, 256, 0, stream>>>(x, w, amax);
    quant_kernel<<<4096, 256, 0, stream>>>(x, w, aq, wq, amax);

    dim3 grid(M / 256, N / 256);
    gemm_i8_kernel<<<grid, 512, 0, stream>>>(aq, wq, out, amax);
}

// Round 6
// 419.287 us; speedup vs baseline: 1.2855x; 1.0554x over previous
//
#include <hip/hip_runtime.h>

#define FP8_MAX_F 448.0f

static constexpr int M = 8192;   // 4*2048
static constexpr int N = 8192;
static constexpr int K = 4096;

typedef __attribute__((ext_vector_type(4))) int i32x4;

#define AS1 __attribute__((address_space(1)))
#define AS3 __attribute__((address_space(3)))
// sched_barrier fences pin the phase structure (register-only MFMAs could
// otherwise migrate across the asm s_barrier).
#define BARRIER() do { \
        __builtin_amdgcn_sched_barrier(0); \
        asm volatile("s_barrier" ::: "memory"); \
        __builtin_amdgcn_sched_barrier(0); \
    } while (0)
#define VMCNT(n)  asm volatile("s_waitcnt vmcnt(" #n ")" ::: "memory")

// ---------------- amax over both tensors (exact, bit-trick atomicMax) --------
__global__ void amax_kernel(const float* __restrict__ x, const float* __restrict__ w,
                            unsigned* __restrict__ out) {
    const long n4x = (long)M * K / 4;
    const long n4t = n4x + (long)N * K / 4;
    unsigned lx = 0u, lw = 0u;
    const long stride = (long)gridDim.x * blockDim.x;
    for (long i = (long)blockIdx.x * blockDim.x + threadIdx.x; i < n4t; i += stride) {
        if (i < n4x) {
            float4 v = ((const float4*)x)[i];
            unsigned a0 = __float_as_uint(v.x) & 0x7fffffffu;
            unsigned a1 = __float_as_uint(v.y) & 0x7fffffffu;
            unsigned a2 = __float_as_uint(v.z) & 0x7fffffffu;
            unsigned a3 = __float_as_uint(v.w) & 0x7fffffffu;
            lx = max(lx, max(max(a0, a1), max(a2, a3)));
        } else {
            float4 v = ((const float4*)w)[i - n4x];
            unsigned a0 = __float_as_uint(v.x) & 0x7fffffffu;
            unsigned a1 = __float_as_uint(v.y) & 0x7fffffffu;
            unsigned a2 = __float_as_uint(v.z) & 0x7fffffffu;
            unsigned a3 = __float_as_uint(v.w) & 0x7fffffffu;
            lw = max(lw, max(max(a0, a1), max(a2, a3)));
        }
    }
    #pragma unroll
    for (int off = 32; off > 0; off >>= 1) {
        lx = max(lx, (unsigned)__shfl_down((int)lx, off, 64));
        lw = max(lw, (unsigned)__shfl_down((int)lw, off, 64));
    }
    __shared__ unsigned smx[4], smw[4];
    if ((threadIdx.x & 63) == 0) { smx[threadIdx.x >> 6] = lx; smw[threadIdx.x >> 6] = lw; }
    __syncthreads();
    if (threadIdx.x == 0) {
        atomicMax(&out[0], max(max(smx[0], smx[1]), max(smx[2], smx[3])));
        atomicMax(&out[1], max(max(smw[0], smw[1]), max(smw[2], smw[3])));
    }
}

// ---------------- quantize both tensors to int8 codes, pre-swizzled layout ---
// Logical code (row r, k) stored with its 16B chunk XOR-permuted within each
// 64B k-group: chunk' = (k>>4)&3 XOR ((r>>1)&3). GEMM stages linearly
// (global_load_lds) and applies the same XOR on ds_read (T2, rule 21).
__device__ __forceinline__ signed char quant1(float v, float s) {
    float f = fminf(fmaxf(v * s, -FP8_MAX_F), FP8_MAX_F);
    return (signed char)(int)rintf(f / FP8_MAX_F * 127.0f);
}

__global__ void quant_kernel(const float* __restrict__ x, const float* __restrict__ w,
                             signed char* __restrict__ qx, signed char* __restrict__ qw,
                             const unsigned* __restrict__ amax_bits) {
    const float ax = fmaxf(__uint_as_float(amax_bits[0]), 1e-12f);
    const float aw = fmaxf(__uint_as_float(amax_bits[1]), 1e-12f);
    const float sxv = FP8_MAX_F / ax;
    const float swv = FP8_MAX_F / aw;
    const long cx = (long)M * K / 16;
    const long ct = cx + (long)N * K / 16;
    const long stride = (long)gridDim.x * blockDim.x;
    for (long ci = (long)blockIdx.x * blockDim.x + threadIdx.x; ci < ct; ci += stride) {
        const float* src; signed char* dst; float s; long c;
        if (ci < cx) { src = x; dst = qx; s = sxv; c = ci; }
        else         { src = w; dst = qw; s = swv; c = ci - cx; }
        const long r = c >> 8;              // K/16 = 256 chunks per row
        const int  cr = (int)(c & 255);
        const float4* in = (const float4*)(src + r * K + cr * 16);
        signed char ob[16];
        #pragma unroll
        for (int j = 0; j < 4; ++j) {
            float4 v = in[j];
            ob[j * 4 + 0] = quant1(v.x, s);
            ob[j * 4 + 1] = quant1(v.y, s);
            ob[j * 4 + 2] = quant1(v.z, s);
            ob[j * 4 + 3] = quant1(v.w, s);
        }
        const int osub = (cr & 3) ^ ((int)(r >> 1) & 3);
        *(int4*)(dst + r * K + ((long)((cr & ~3) + osub)) * 16) = *(const int4*)ob;
    }
}

// ---------------- int8 GEMM: C[m][n] = sum_k A[m][k]*B[n][k] ----------------
// 256x256 tile, BK=64, 512 threads = 8 waves (2M x 4N), wave output 128x64.
// T3 fine interleave: each K-tile = 4 phases; phase p = {2-4 ds_reads of
// tile t+1's subtile (+2 stage issues at p=0,1)} -> barrier -> 8-MFMA
// cluster (acc rows 2p,2p+1 x 4) -> barrier. Reads consumed 5-8 phases after
// issue (lgkm waits free). 4-deep LDS circular buffer, vmcnt(4) once per
// tile at phase 3 (T4), setprio around clusters (T5), T2 swizzled ds_read.
__global__ __launch_bounds__(512, 2) void gemm_i8_kernel(
    const signed char* __restrict__ Aq, const signed char* __restrict__ Bq,
    float* __restrict__ C, const unsigned* __restrict__ amax_bits)
{
    __shared__ signed char lds[4][2][256 * 64];   // [buf][A/B][row*64 + col]

    const int tid  = threadIdx.x;
    const int wid  = tid >> 6;
    const int lane = tid & 63;
    const int wm = wid >> 2;          // 0..1  (M half)
    const int wn = wid & 3;           // 0..3  (N quarter)
    const int fr = lane & 15;
    const int fq = lane >> 4;

    const long row0 = (long)blockIdx.x * 256;
    const long col0 = (long)blockIdx.y * 256;

    const signed char* Ablk = Aq + row0 * K;
    const signed char* Bblk = Bq + col0 * K;

    // staging: one issue = 512 thr x 16B = 128 rows x 64B (linear LDS dest)
    const long stag_off = (long)(tid >> 2) * K + (long)(tid & 3) * 16;

    // swizzled ds_read offsets (XOR constant across mi/ni: steps are x16 rows)
    const int arow = wm * 128 + fr;
    const int aoff = arow * 64 + ((fq ^ ((arow >> 1) & 3)) * 16);
    const int brow = wn * 64 + fr;
    const int boff = brow * 64 + ((fq ^ ((brow >> 1) & 3)) * 16);

    i32x4 acc[8][4] = {};
    i32x4 afR[2][8];      // parity-double-buffered A fragments
    i32x4 bR[2][4];       // parity-double-buffered B fragments

#define STAGE_A(st) do { \
        const signed char* ga = Ablk + (long)(st) * 64 + stag_off; \
        signed char* lA = &lds[(st) & 3][0][0]; \
        __builtin_amdgcn_global_load_lds((const AS1 void*)ga, \
            (AS3 void*)(lA + wid * 1024), 16, 0, 0); \
        __builtin_amdgcn_global_load_lds((const AS1 void*)(ga + 128L * K), \
            (AS3 void*)(lA + 8192 + wid * 1024), 16, 0, 0); \
    } while (0)

#define STAGE_B(st) do { \
        const signed char* gb = Bblk + (long)(st) * 64 + stag_off; \
        signed char* lB = &lds[(st) & 3][1][0]; \
        __builtin_amdgcn_global_load_lds((const AS1 void*)gb, \
            (AS3 void*)(lB + wid * 1024), 16, 0, 0); \
        __builtin_amdgcn_global_load_lds((const AS1 void*)(gb + 128L * K), \
            (AS3 void*)(lB + 8192 + wid * 1024), 16, 0, 0); \
    } while (0)

#define CLUSTER(CUR, P) do { \
        BARRIER(); \
        __builtin_amdgcn_s_setprio(1); \
        _Pragma("unroll") \
        for (int ni = 0; ni < 4; ++ni) { \
            acc[2*(P)][ni]   = __builtin_amdgcn_mfma_i32_16x16x64_i8( \
                afR[CUR][2*(P)],   bR[CUR][ni], acc[2*(P)][ni],   0, 0, 0); \
            acc[2*(P)+1][ni] = __builtin_amdgcn_mfma_i32_16x16x64_i8( \
                afR[CUR][2*(P)+1], bR[CUR][ni], acc[2*(P)+1][ni], 0, 0, 0); \
        } \
        __builtin_amdgcn_s_setprio(0); \
        BARRIER(); \
    } while (0)

    // One K-tile = 4 fine phases. T1 = tile whose subtiles we prefetch.
#define TILE_P(CUR, NXT, T1, S0_STMT, S1_STMT, VM_STMT, DO_RD) do { \
        const signed char* la_ = &lds[(T1) & 3][0][0]; \
        const signed char* lb_ = &lds[(T1) & 3][1][0]; \
        if (DO_RD) { \
            afR[NXT][0] = *(const i32x4*)(la_ + aoff + 0 * 1024); \
            afR[NXT][1] = *(const i32x4*)(la_ + aoff + 1 * 1024); \
        } \
        S0_STMT; \
        CLUSTER(CUR, 0); \
        if (DO_RD) { \
            afR[NXT][2] = *(const i32x4*)(la_ + aoff + 2 * 1024); \
            afR[NXT][3] = *(const i32x4*)(la_ + aoff + 3 * 1024); \
            bR[NXT][0]  = *(const i32x4*)(lb_ + boff + 0 * 1024); \
        } \
        S1_STMT; \
        CLUSTER(CUR, 1); \
        if (DO_RD) { \
            afR[NXT][4] = *(const i32x4*)(la_ + aoff + 4 * 1024); \
            afR[NXT][5] = *(const i32x4*)(la_ + aoff + 5 * 1024); \
            bR[NXT][1]  = *(const i32x4*)(lb_ + boff + 1 * 1024); \
        } \
        CLUSTER(CUR, 2); \
        if (DO_RD) { \
            afR[NXT][6] = *(const i32x4*)(la_ + aoff + 6 * 1024); \
            afR[NXT][7] = *(const i32x4*)(la_ + aoff + 7 * 1024); \
            bR[NXT][2]  = *(const i32x4*)(lb_ + boff + 2 * 1024); \
            bR[NXT][3]  = *(const i32x4*)(lb_ + boff + 3 * 1024); \
        } \
        VM_STMT; \
        CLUSTER(CUR, 3); \
    } while (0)

    // prologue: stage tiles 0,1,2 (12 issues); drain to 4 -> tiles 0,1 resident
    STAGE_A(0); STAGE_B(0);
    STAGE_A(1); STAGE_B(1);
    STAGE_A(2); STAGE_B(2);
    VMCNT(4);
    BARRIER();
    #pragma unroll
    for (int mi = 0; mi < 8; ++mi)
        afR[0][mi] = *(const i32x4*)(&lds[0][0][0] + aoff + mi * 1024);
    #pragma unroll
    for (int ni = 0; ni < 4; ++ni)
        bR[0][ni] = *(const i32x4*)(&lds[0][1][0] + boff + ni * 1024);

    // main loop: tiles 0..59 (stages 3..63 issued up to t=60 tail)
    #pragma unroll 1
    for (int t = 0; t < 60; t += 2) {
        TILE_P(0, 1, t + 1, STAGE_A(t + 3), STAGE_B(t + 3), VMCNT(4), 1);
        TILE_P(1, 0, t + 2, STAGE_A(t + 4), STAGE_B(t + 4), VMCNT(4), 1);
    }
    // tail
    TILE_P(0, 1, 61, STAGE_A(63), STAGE_B(63), VMCNT(4), 1);   // t=60
    TILE_P(1, 0, 62, (void)0,     (void)0,     VMCNT(0), 1);   // t=61
    TILE_P(0, 1, 63, (void)0,     (void)0,     (void)0,  1);   // t=62
    TILE_P(1, 0, 63, (void)0,     (void)0,     (void)0,  0);   // t=63 (no rd)

#undef TILE_P
#undef CLUSTER
#undef STAGE_B
#undef STAGE_A

    const float ax = fmaxf(__uint_as_float(amax_bits[0]), 1e-12f);
    const float aw = fmaxf(__uint_as_float(amax_bits[1]), 1e-12f);
    const float factor = ax * aw * (1.0f / (127.0f * 127.0f));

    #pragma unroll
    for (int mi = 0; mi < 8; ++mi) {
        #pragma unroll
        for (int ni = 0; ni < 4; ++ni) {
            const long col = col0 + wn * 64 + ni * 16 + fr;
            #pragma unroll
            for (int j = 0; j < 4; ++j) {
                const long row = row0 + wm * 128 + mi * 16 + fq * 4 + j;
                C[row * N + col] = (float)acc[mi][ni][j] * factor;
            }
        }
    }
}

extern "C" void kernel_launch(void* const* d_in, const int* in_sizes, int n_in,
                              void* d_out, int out_size, void* d_ws, size_t ws_size,
                              hipStream_t stream) {
    const float* x = (const float*)d_in[0];   // [4,2048,4096] -> [M,K]
    const float* w = (const float*)d_in[1];   // [N,K]
    float* out = (float*)d_out;               // [M,N]

    unsigned char* ws = (unsigned char*)d_ws;
    unsigned* amax = (unsigned*)ws;                        // 2 uints
    signed char* aq = (signed char*)(ws + 256);            // M*K int8 (swizzled)
    signed char* wq = aq + (long)M * K;                    // N*K int8 (swizzled)

    hipMemsetAsync(amax, 0, 2 * sizeof(unsigned), stream);
    amax_kernel<<<2048, 256, 0, stream>>>(x, w, amax);
    quant_kernel<<<4096, 256, 0, stream>>>(x, w, aq, wq, amax);

    dim3 grid(M / 256, N / 256);
    gemm_i8_kernel<<<grid, 512, 0, stream>>>(aq, wq, out, amax);
}